// Round 1
// baseline (215.606 us; speedup 1.0000x reference)
//
#include <hip/hip_runtime.h>
#include <hip/hip_bf16.h>
#include <math.h>

#define BATCH 8192
#define F 256
#define G 32
#define W 512
#define BM 128
#define BN 128
#define ASTR 72
#define BSTR 72
#define NCHUNK 132   // 128 spline chunks (2 features x 32 g) + 4 skip chunks (64 k each)

typedef float f32x4 __attribute__((ext_vector_type(4)));
typedef short s16x8 __attribute__((ext_vector_type(8)));

__device__ __forceinline__ short f2bf(float f) {
  unsigned int u = __builtin_bit_cast(unsigned int, f);
  u += 0x7fffu + ((u >> 16) & 1u);
  return (short)(u >> 16);
}

__device__ __forceinline__ float knotv(int i) {
  int j = i - 3;
  j = j < 0 ? 0 : (j > 29 ? 29 : j);
  return (float)j * (1.0f / 29.0f);
}

__device__ __forceinline__ float fdiv_fast(float a, float b) {
  return a * __builtin_amdgcn_rcpf(b);
}

__global__ __launch_bounds__(512, 1) void kan_gemm(
    const float* __restrict__ inp, const float* __restrict__ shift,
    const float* __restrict__ lscale, const float* __restrict__ coeffs,
    const float* __restrict__ bias, const float* __restrict__ skip_w,
    const float* __restrict__ skip_b, float* __restrict__ out)
{
  __shared__ short Alds[BM * ASTR];
  __shared__ short Blds[BN * BSTR];
  __shared__ float sh_scale[F];
  __shared__ float sh_shift[F];

  const int tid = threadIdx.x;
  const int lane = tid & 63;
  const int wid = tid >> 6;
  const int nt = blockIdx.x & 3;
  const int mt = blockIdx.x >> 2;
  const int m0 = mt * BM;
  const int n0 = nt * BN;

  if (tid < F) {
    float ls = lscale[tid];
    // softplus(ls) + 0.001 (numerically stable)
    sh_scale[tid] = fmaxf(ls, 0.0f) + log1pf(expf(-fabsf(ls))) + 0.001f;
    sh_shift[tid] = shift[tid];
  }
  __syncthreads();

  const int wm = wid >> 2;   // 0..1  (64-row slab)
  const int wn = wid & 3;    // 0..3  (32-col slab)
  const int l15 = lane & 15;
  const int lq = lane >> 4;

  f32x4 acc[4][2];
  #pragma unroll
  for (int i = 0; i < 4; ++i)
    #pragma unroll
    for (int j = 0; j < 2; ++j)
      acc[i][j] = (f32x4){0.f, 0.f, 0.f, 0.f};

  for (int c = 0; c < NCHUNK; ++c) {
    // ---------------- staging ----------------
    if (tid < 256) {
      // A-tile: 128 rows x 64 k (2 features' basis, or a 64-wide input slice)
      const int bp = tid & 127;
      const int fi = tid >> 7;          // 0..1
      short* arow = &Alds[bp * ASTR + fi * 32];
      if (c < 128) {
        const int f = 2 * c + fi;
        const float x = inp[(m0 + bp) * F + f];
        const float z = (x - sh_shift[f]) * sh_scale[f];
        const float sg = 1.0f / (1.0f + expf(-z));
        // zero the 32-wide row segment
        s16x8 zz = {0, 0, 0, 0, 0, 0, 0, 0};
        ((s16x8*)arow)[0] = zz;
        ((s16x8*)arow)[1] = zz;
        ((s16x8*)arow)[2] = zz;
        ((s16x8*)arow)[3] = zz;
        // cubic B-spline: span + de Boor (knots uniform: (j-3)/29 clamped)
        int s0 = (int)floorf(sg * 29.0f);
        s0 = s0 < 0 ? 0 : (s0 > 28 ? 28 : s0);
        const int sp = s0 + 3;
        float Nv[4], lef[4], rig[4];
        Nv[0] = 1.0f;
        #pragma unroll
        for (int r = 1; r <= 3; ++r) {
          lef[r] = sg - knotv(sp + 1 - r);
          rig[r] = knotv(sp + r) - sg;
          float saved = 0.0f;
          #pragma unroll
          for (int j = 0; j < r; ++j) {
            float temp = fdiv_fast(Nv[j], rig[j + 1] + lef[r - j]);
            Nv[j] = saved + rig[j + 1] * temp;
            saved = lef[r - j] * temp;
          }
          Nv[r] = saved;
        }
        arow[s0 + 0] = f2bf(Nv[0]);
        arow[s0 + 1] = f2bf(Nv[1]);
        arow[s0 + 2] = f2bf(Nv[2]);
        arow[s0 + 3] = f2bf(Nv[3]);
      } else {
        // skip-path A: copy a 32-wide slice of inputs as bf16
        const int sb = (c - 128) * 64 + fi * 32;
        const float* ip = &inp[(m0 + bp) * F + sb];
        #pragma unroll
        for (int i = 0; i < 32; i += 8) {
          s16x8 h;
          #pragma unroll
          for (int j = 0; j < 8; ++j) h[j] = f2bf(ip[i + j]);
          *(s16x8*)&arow[i] = h;
        }
      }
    } else {
      // B-tile, transposed into LDS: Blds[w][k_local], k_local in [0,64)
      const int tt = tid - 256;
      const int w = tt & 127;
      const int gq = tt >> 7;           // 0..1 -> k_local halves of 32
      const float* base;
      if (c < 128) base = coeffs + (size_t)(c * 64 + gq * 32) * W;
      else         base = skip_w + (size_t)((c - 128) * 64 + gq * 32) * W;
      const float* p = base + n0 + w;
      short* brow = &Blds[w * BSTR + gq * 32];
      #pragma unroll
      for (int g8 = 0; g8 < 4; ++g8) {
        float v[8];
        #pragma unroll
        for (int j = 0; j < 8; ++j) v[j] = p[(size_t)(g8 * 8 + j) * W];
        s16x8 h;
        #pragma unroll
        for (int j = 0; j < 8; ++j) h[j] = f2bf(v[j]);
        *(s16x8*)&brow[g8 * 8] = h;
      }
    }
    __syncthreads();

    // ---------------- MFMA ----------------
    #pragma unroll
    for (int kk = 0; kk < 2; ++kk) {
      s16x8 af[4];
      #pragma unroll
      for (int mf = 0; mf < 4; ++mf)
        af[mf] = *(const s16x8*)&Alds[(wm * 64 + mf * 16 + l15) * ASTR + kk * 32 + lq * 8];
      #pragma unroll
      for (int nf = 0; nf < 2; ++nf) {
        s16x8 bfv = *(const s16x8*)&Blds[(wn * 32 + nf * 16 + l15) * BSTR + kk * 32 + lq * 8];
        #pragma unroll
        for (int mf = 0; mf < 4; ++mf)
          acc[mf][nf] = __builtin_amdgcn_mfma_f32_16x16x32_bf16(af[mf], bfv, acc[mf][nf], 0, 0, 0);
      }
    }
    __syncthreads();
  }

  // ---------------- epilogue: + bias + skip_b, write fp32 "combined" ----------------
  #pragma unroll
  for (int nf = 0; nf < 2; ++nf) {
    const int col = n0 + wn * 32 + nf * 16 + l15;
    const float badd = bias[col] + skip_b[col];
    #pragma unroll
    for (int mf = 0; mf < 4; ++mf) {
      const int r0 = m0 + wm * 64 + mf * 16 + lq * 4;
      #pragma unroll
      for (int r = 0; r < 4; ++r)
        out[(size_t)(r0 + r) * W + col] = acc[mf][nf][r] + badd;
    }
  }
}

__global__ __launch_bounds__(256, 1) void ln_gelu(
    float* __restrict__ out, const float* __restrict__ gamma,
    const float* __restrict__ beta)
{
  const int lane = threadIdx.x & 63;
  const int wid = threadIdx.x >> 6;
  const int row = blockIdx.x * 4 + wid;
  float* p = out + (size_t)row * W + lane * 8;
  float4 a = *(const float4*)p;
  float4 b = *(const float4*)(p + 4);
  float v[8] = {a.x, a.y, a.z, a.w, b.x, b.y, b.z, b.w};
  float s = 0.f, q = 0.f;
  #pragma unroll
  for (int j = 0; j < 8; ++j) { s += v[j]; q += v[j] * v[j]; }
  #pragma unroll
  for (int m = 1; m < 64; m <<= 1) {
    s += __shfl_xor(s, m);
    q += __shfl_xor(q, m);
  }
  const float mu = s * (1.0f / 512.0f);
  const float var = q * (1.0f / 512.0f) - mu * mu;
  const float inv = rsqrtf(var + 1e-5f);
  const float4 g0 = *(const float4*)(gamma + lane * 8);
  const float4 g1 = *(const float4*)(gamma + lane * 8 + 4);
  const float4 b0 = *(const float4*)(beta + lane * 8);
  const float4 b1 = *(const float4*)(beta + lane * 8 + 4);
  float gm[8] = {g0.x, g0.y, g0.z, g0.w, g1.x, g1.y, g1.z, g1.w};
  float bt[8] = {b0.x, b0.y, b0.z, b0.w, b1.x, b1.y, b1.z, b1.w};
  float o[8];
  #pragma unroll
  for (int j = 0; j < 8; ++j) {
    float x = (v[j] - mu) * inv * gm[j] + bt[j];
    o[j] = 0.5f * x * (1.0f + erff(x * 0.70710678f));
  }
  float4 w0 = {o[0], o[1], o[2], o[3]};
  float4 w1 = {o[4], o[5], o[6], o[7]};
  *(float4*)p = w0;
  *(float4*)(p + 4) = w1;
}

extern "C" void kernel_launch(void* const* d_in, const int* in_sizes, int n_in,
                              void* d_out, int out_size, void* d_ws, size_t ws_size,
                              hipStream_t stream) {
  (void)in_sizes; (void)n_in; (void)out_size; (void)d_ws; (void)ws_size;
  const float* inp    = (const float*)d_in[0];
  const float* shift  = (const float*)d_in[1];
  const float* lscale = (const float*)d_in[2];
  const float* coeffs = (const float*)d_in[3];
  const float* bias   = (const float*)d_in[4];
  const float* skip_w = (const float*)d_in[5];
  const float* skip_b = (const float*)d_in[6];
  const float* gamma  = (const float*)d_in[7];
  const float* beta   = (const float*)d_in[8];
  float* out = (float*)d_out;

  kan_gemm<<<dim3(256), dim3(512), 0, stream>>>(
      inp, shift, lscale, coeffs, bias, skip_w, skip_b, out);
  ln_gelu<<<dim3(BATCH / 4), dim3(256), 0, stream>>>(out, gamma, beta);
}

// Round 2
// 185.621 us; speedup vs baseline: 1.1615x; 1.1615x over previous
//
#include <hip/hip_runtime.h>
#include <hip/hip_bf16.h>
#include <math.h>

#define BATCH 8192
#define F 256
#define G 32
#define W 512
#define BM 128
#define NCHUNK 132   // 128 spline chunks (2 features x 32 g) + 4 skip chunks (64 k each)

typedef float f32x4 __attribute__((ext_vector_type(4)));
typedef short s16x8 __attribute__((ext_vector_type(8)));

__device__ __forceinline__ short f2bf(float f) {
  unsigned int u = __builtin_bit_cast(unsigned int, f);
  u += 0x7fffu + ((u >> 16) & 1u);
  return (short)(u >> 16);
}

__device__ __forceinline__ float knotv(int i) {
  int j = i - 3;
  j = j < 0 ? 0 : (j > 29 ? 29 : j);
  return (float)j * (1.0f / 29.0f);
}

__device__ __forceinline__ float fdiv_fast(float a, float b) {
  return a * __builtin_amdgcn_rcpf(b);
}

// Issue the 32 global loads for chunk c into bpref (B staging, fragment-major gather).
__device__ __forceinline__ void issue_b(int c, int uu, int n0,
                                        const float* __restrict__ coeffs,
                                        const float* __restrict__ skip_w,
                                        float (&r)[4][8]) {
  const float* base = (c < 128) ? (coeffs + (size_t)c * 64 * W)
                                : (skip_w + (size_t)(c - 128) * 64 * W);
  const int kk = (uu >> 6) & 1;
  const int lq = (uu >> 4) & 3;
  const int l15 = uu & 15;
  const int u7 = uu >> 7;
  #pragma unroll
  for (int s = 0; s < 4; ++s) {
    const int w = (2 * s + u7) * 16 + l15;
    const float* p = base + (size_t)(kk * 32 + lq * 8) * W + n0 + w;
    #pragma unroll
    for (int j = 0; j < 8; ++j) r[s][j] = p[(size_t)j * W];
  }
}

__global__ __launch_bounds__(512, 1) void kan_gemm(
    const float* __restrict__ inp, const float* __restrict__ shift,
    const float* __restrict__ lscale, const float* __restrict__ coeffs,
    const float* __restrict__ bias, const float* __restrict__ skip_w,
    const float* __restrict__ skip_b, float* __restrict__ out)
{
  __shared__ short Abuf[2][8192];            // 2 x 16KB, fragment-major
  __shared__ short Bbuf[2][8192];            // 2 x 16KB, fragment-major
  __shared__ unsigned short sgl[F * 128];    // 64KB: sg[f][row], u16-quantized

  const int tid = threadIdx.x;
  const int lane = tid & 63;
  const int wid = tid >> 6;

  // XCD-bijective swizzle: 256 blocks = 8 XCDs x 32; same-mt blocks share an XCD.
  const int nb = (blockIdx.x & 7) * 32 + (blockIdx.x >> 3);
  const int mt = nb >> 2;
  const int nt = nb & 3;
  const int m0 = mt * BM;
  const int n0 = nt * 128;

  // ---- issue B prefetch for chunk 0 ASAP (B-waves only) ----
  float bpref[4][8];
  if (tid >= 256) issue_b(0, tid - 256, n0, coeffs, skip_w, bpref);

  // ---- phase 0: softplus scale / shift into (aliased) Abuf[0] ----
  float* shf = (float*)&Abuf[0][0];          // [0..255] scale, [256..511] shift
  if (tid < 256) {
    float ls = lscale[tid];
    shf[tid] = fmaxf(ls, 0.0f) + __logf(1.0f + __expf(-fabsf(ls))) + 0.001f;
    shf[256 + tid] = shift[tid];
  }
  __syncthreads();

  // ---- prologue: all 128x256 sigmoids once, quantized u16 into sgl[f][row] ----
  {
    const int row = tid & 127;
    const int q = tid >> 7;
    const float* ip = inp + (size_t)(m0 + row) * F + q * 64;
    #pragma unroll
    for (int i = 0; i < 16; ++i) {
      float4 v = *(const float4*)(ip + i * 4);
      float vv[4] = {v.x, v.y, v.z, v.w};
      #pragma unroll
      for (int j = 0; j < 4; ++j) {
        const int f = q * 64 + i * 4 + j;
        const float z = (vv[j] - shf[256 + f]) * shf[f];
        const float sg = 1.0f / (1.0f + __expf(-z));
        sgl[f * 128 + row] = (unsigned short)fminf(sg * 65536.0f, 65535.0f);
      }
    }
  }
  __syncthreads();

  const int wm = wid >> 2;   // 0..1
  const int wn = wid & 3;    // 0..3

  f32x4 acc[4][2];
  #pragma unroll
  for (int i = 0; i < 4; ++i)
    #pragma unroll
    for (int j = 0; j < 2; ++j)
      acc[i][j] = (f32x4){0.f, 0.f, 0.f, 0.f};

  for (int c = 0; c < NCHUNK; ++c) {
    short* Ab = Abuf[c & 1];
    short* Bb = Bbuf[c & 1];

    // ================= phase 1 =================
    if (c < 128) {
      // zero the A buffer (contiguous, conflict-free, all 512 threads)
      s16x8 z = {0, 0, 0, 0, 0, 0, 0, 0};
      ((s16x8*)Ab)[tid * 2] = z;
      ((s16x8*)Ab)[tid * 2 + 1] = z;
    } else if (tid < 256) {
      // skip chunks: dense A = bf16 input slice, fragment-major
      const int bp = tid & 127, fi = tid >> 7;
      const int sb = (c - 128) * 64 + fi * 32;
      const float* ip = inp + (size_t)(m0 + bp) * F + sb;
      const int rg = bp >> 4, l15b = bp & 15;
      #pragma unroll
      for (int lq2 = 0; lq2 < 4; ++lq2) {
        s16x8 h;
        #pragma unroll
        for (int j = 0; j < 8; ++j) h[j] = f2bf(ip[lq2 * 8 + j]);
        *(s16x8*)&Ab[((rg * 2 + fi) * 64 + lq2 * 16 + l15b) * 8] = h;
      }
    }
    if (tid >= 256) {
      const int uu = tid - 256;
      // cvt + contiguous (conflict-free) writes of the prefetched B tile
      #pragma unroll
      for (int s = 0; s < 4; ++s) {
        s16x8 h;
        #pragma unroll
        for (int j = 0; j < 8; ++j) h[j] = f2bf(bpref[s][j]);
        *(s16x8*)&Bb[(s * 256 + uu) * 8] = h;
      }
      if (c + 1 < NCHUNK) issue_b(c + 1, uu, n0, coeffs, skip_w, bpref);
    }
    __syncthreads();   // b1

    // ================= phase 2 =================
    if (c < 128 && tid < 256) {
      const int bp = tid & 127, fi = tid >> 7;
      const int f = 2 * c + fi;
      const float sg = ((float)sgl[f * 128 + bp] + 0.5f) * (1.0f / 65536.0f);
      int s0 = (int)floorf(sg * 29.0f);
      s0 = s0 < 0 ? 0 : (s0 > 28 ? 28 : s0);
      const int sp = s0 + 3;
      float Nv[4], lef[4], rig[4];
      Nv[0] = 1.0f;
      #pragma unroll
      for (int r = 1; r <= 3; ++r) {
        lef[r] = sg - knotv(sp + 1 - r);
        rig[r] = knotv(sp + r) - sg;
        float saved = 0.0f;
        #pragma unroll
        for (int j = 0; j < r; ++j) {
          float temp = fdiv_fast(Nv[j], rig[j + 1] + lef[r - j]);
          Nv[j] = saved + rig[j + 1] * temp;
          saved = lef[r - j] * temp;
        }
        Nv[r] = saved;
      }
      const int rg = bp >> 4, l15b = bp & 15;
      #pragma unroll
      for (int t = 0; t < 4; ++t) {
        const int g = s0 + t;
        Ab[((rg * 2 + fi) * 64 + (g >> 3) * 16 + l15b) * 8 + (g & 7)] = f2bf(Nv[t]);
      }
    }
    // early B-frag reads (visible since b1; contiguous, conflict-free)
    s16x8 bfv[2][2];
    #pragma unroll
    for (int nf = 0; nf < 2; ++nf)
      #pragma unroll
      for (int kk = 0; kk < 2; ++kk)
        bfv[nf][kk] = *(const s16x8*)&Bb[(((wn * 2 + nf) * 2 + kk) * 64 + lane) * 8];
    __syncthreads();   // b2

    // ================= MFMA =================
    #pragma unroll
    for (int kk = 0; kk < 2; ++kk) {
      #pragma unroll
      for (int mf = 0; mf < 4; ++mf) {
        s16x8 af = *(const s16x8*)&Ab[(((wm * 4 + mf) * 2 + kk) * 64 + lane) * 8];
        #pragma unroll
        for (int nf = 0; nf < 2; ++nf)
          acc[mf][nf] = __builtin_amdgcn_mfma_f32_16x16x32_bf16(af, bfv[nf][kk], acc[mf][nf], 0, 0, 0);
      }
    }
  }

  // ---- epilogue: + bias + skip_b, write fp32 "combined" ----
  const int l15 = lane & 15;
  const int lq = lane >> 4;
  #pragma unroll
  for (int nf = 0; nf < 2; ++nf) {
    const int col = n0 + wn * 32 + nf * 16 + l15;
    const float badd = bias[col] + skip_b[col];
    #pragma unroll
    for (int mf = 0; mf < 4; ++mf) {
      const int r0 = m0 + wm * 64 + mf * 16 + lq * 4;
      #pragma unroll
      for (int r = 0; r < 4; ++r)
        out[(size_t)(r0 + r) * W + col] = acc[mf][nf][r] + badd;
    }
  }
}

__global__ __launch_bounds__(256, 1) void ln_gelu(
    float* __restrict__ out, const float* __restrict__ gamma,
    const float* __restrict__ beta)
{
  const int lane = threadIdx.x & 63;
  const int wid = threadIdx.x >> 6;
  const int row = blockIdx.x * 4 + wid;
  float* p = out + (size_t)row * W + lane * 8;
  float4 a = *(const float4*)p;
  float4 b = *(const float4*)(p + 4);
  float v[8] = {a.x, a.y, a.z, a.w, b.x, b.y, b.z, b.w};
  float s = 0.f, q = 0.f;
  #pragma unroll
  for (int j = 0; j < 8; ++j) { s += v[j]; q += v[j] * v[j]; }
  #pragma unroll
  for (int m = 1; m < 64; m <<= 1) {
    s += __shfl_xor(s, m);
    q += __shfl_xor(q, m);
  }
  const float mu = s * (1.0f / 512.0f);
  const float var = q * (1.0f / 512.0f) - mu * mu;
  const float inv = rsqrtf(var + 1e-5f);
  const float4 g0 = *(const float4*)(gamma + lane * 8);
  const float4 g1 = *(const float4*)(gamma + lane * 8 + 4);
  const float4 b0 = *(const float4*)(beta + lane * 8);
  const float4 b1 = *(const float4*)(beta + lane * 8 + 4);
  float gm[8] = {g0.x, g0.y, g0.z, g0.w, g1.x, g1.y, g1.z, g1.w};
  float bt[8] = {b0.x, b0.y, b0.z, b0.w, b1.x, b1.y, b1.z, b1.w};
  float o[8];
  #pragma unroll
  for (int j = 0; j < 8; ++j) {
    float x = (v[j] - mu) * inv * gm[j] + bt[j];
    o[j] = 0.5f * x * (1.0f + erff(x * 0.70710678f));
  }
  float4 w0 = {o[0], o[1], o[2], o[3]};
  float4 w1 = {o[4], o[5], o[6], o[7]};
  *(float4*)p = w0;
  *(float4*)(p + 4) = w1;
}

extern "C" void kernel_launch(void* const* d_in, const int* in_sizes, int n_in,
                              void* d_out, int out_size, void* d_ws, size_t ws_size,
                              hipStream_t stream) {
  (void)in_sizes; (void)n_in; (void)out_size; (void)d_ws; (void)ws_size;
  const float* inp    = (const float*)d_in[0];
  const float* shift  = (const float*)d_in[1];
  const float* lscale = (const float*)d_in[2];
  const float* coeffs = (const float*)d_in[3];
  const float* bias   = (const float*)d_in[4];
  const float* skip_w = (const float*)d_in[5];
  const float* skip_b = (const float*)d_in[6];
  const float* gamma  = (const float*)d_in[7];
  const float* beta   = (const float*)d_in[8];
  float* out = (float*)d_out;

  kan_gemm<<<dim3(256), dim3(512), 0, stream>>>(
      inp, shift, lscale, coeffs, bias, skip_w, skip_b, out);
  ln_gelu<<<dim3(BATCH / 4), dim3(256), 0, stream>>>(out, gamma, beta);
}

// Round 3
// 151.325 us; speedup vs baseline: 1.4248x; 1.2266x over previous
//
#include <hip/hip_runtime.h>
#include <hip/hip_bf16.h>
#include <math.h>

#define BATCH 8192
#define F 256
#define G 32
#define W 512
#define NCHUNK 132   // 128 spline chunks (2 features x 32 g) + 4 skip chunks (64 k each)

typedef float f32x4 __attribute__((ext_vector_type(4)));
typedef short s16x8 __attribute__((ext_vector_type(8)));

__device__ __forceinline__ short f2bf(float f) {
  unsigned int u = __builtin_bit_cast(unsigned int, f);
  u += 0x7fffu + ((u >> 16) & 1u);
  return (short)(u >> 16);
}

__device__ __forceinline__ float knotv(int i) {
  int j = i - 3;
  j = j < 0 ? 0 : (j > 29 ? 29 : j);
  return (float)j * (1.0f / 29.0f);
}

__device__ __forceinline__ float fdiv_fast(float a, float b) {
  return a * __builtin_amdgcn_rcpf(b);
}

__device__ __forceinline__ void gll16(const void* g, void* l) {
  __builtin_amdgcn_global_load_lds(
      (const __attribute__((address_space(1))) unsigned int*)g,
      (__attribute__((address_space(3))) unsigned int*)l, 16, 0, 0);
}

// ---------------- pre-pass: B (coeffs + skip_w) -> bf16, fragment-major stream ----------------
// tile (c, nt) = 16KB: group g = wn*256 + nf*128 + kk*64 + lane, elem j:
//   w = nt*128 + (2*wn+nf)*16 + (lane&15);  k_local = kk*32 + (lane>>4)*8 + j
__global__ __launch_bounds__(256) void bws_build(
    const float* __restrict__ coeffs, const float* __restrict__ skip_w,
    short* __restrict__ Bws)
{
  const int gid = blockIdx.x * 256 + threadIdx.x;   // 0 .. 540671
  const int c  = gid >> 12;
  const int nt = (gid >> 10) & 3;
  const int g  = gid & 1023;
  const int lane = g & 63, kk = (g >> 6) & 1, nf = (g >> 7) & 1, wn = g >> 8;
  const int w  = nt * 128 + (2 * wn + nf) * 16 + (lane & 15);
  const int kl = kk * 32 + (lane >> 4) * 8;
  const float* src = (c < 128) ? (coeffs + (size_t)(c * 64 + kl) * W + w)
                               : (skip_w + (size_t)((c - 128) * 64 + kl) * W + w);
  s16x8 h;
  #pragma unroll
  for (int j = 0; j < 8; ++j) h[j] = f2bf(src[(size_t)j * W]);
  ((s16x8*)Bws)[gid] = h;
}

// ---------------- pre-pass: skip-A (inputs) -> bf16, fragment-major per (mt, sc) ----------------
// group g = (wm*4+mf)*128 + kk*64 + lane, elem j:
//   row = wm*64 + mf*16 + (lane&15);  k = kk*32 + (lane>>4)*8 + j
__global__ __launch_bounds__(256) void aws_build(
    const float* __restrict__ inp, short* __restrict__ Aws)
{
  const int gid = blockIdx.x * 256 + threadIdx.x;   // 0 .. 262143
  const int mt = gid >> 12;
  const int sc = (gid >> 10) & 3;
  const int g  = gid & 1023;
  const int lane = g & 63, kk = (g >> 6) & 1, mfwm = g >> 7;
  const int mf = mfwm & 3, wm = mfwm >> 2;
  const int row = wm * 64 + mf * 16 + (lane & 15);
  const int k8  = kk * 32 + (lane >> 4) * 8;
  const float* src = inp + (size_t)(mt * 128 + row) * F + sc * 64 + k8;
  s16x8 h;
  #pragma unroll
  for (int j = 0; j < 8; ++j) h[j] = f2bf(src[j]);
  ((s16x8*)Aws)[gid] = h;
}

// ---------------- main GEMM (ws-fed) ----------------
__global__ __launch_bounds__(512, 1) void kan_gemm_v3(
    const float* __restrict__ inp, const float* __restrict__ shift,
    const float* __restrict__ lscale,
    const short* __restrict__ Bws, const short* __restrict__ Aws,
    const float* __restrict__ bias, const float* __restrict__ skip_b,
    float* __restrict__ out)
{
  __shared__ short Abuf[2][8192];
  __shared__ short Bbuf[2][8192];
  __shared__ unsigned short sgl[F * 128];
  __shared__ float shf[2 * F];

  const int tid = threadIdx.x;
  const int lane = tid & 63;
  const int wid = tid >> 6;
  // XCD-bijective swizzle (256 = 8*32)
  const int nb = (blockIdx.x & 7) * 32 + (blockIdx.x >> 3);
  const int mt = nb >> 2, nt = nb & 3;
  const int m0 = mt * 128, n0 = nt * 128;
  const unsigned int ldsoff = (unsigned int)(wid << 10);  // wave byte base

  const s16x8 z8 = {0, 0, 0, 0, 0, 0, 0, 0};

  // stage B[0] ASAP
  {
    const char* gB = (const char*)Bws + (size_t)nt * 16384 + tid * 16;
    gll16(gB,        (char*)Bbuf[0] + ldsoff);
    gll16(gB + 8192, (char*)Bbuf[0] + 8192 + ldsoff);
  }

  if (tid < 256) {
    float ls = lscale[tid];
    shf[tid] = fmaxf(ls, 0.0f) + __logf(1.0f + __expf(-fabsf(ls))) + 0.001f;
    shf[256 + tid] = shift[tid];
  }
  __syncthreads();

  // prologue: all 128x256 sigmoids, u16-quantized; plus zero A[0]
  {
    const int row = tid & 127;
    const int q = tid >> 7;
    const float* ip = inp + (size_t)(m0 + row) * F + q * 64;
    #pragma unroll
    for (int i = 0; i < 16; ++i) {
      float4 v = *(const float4*)(ip + i * 4);
      float vv[4] = {v.x, v.y, v.z, v.w};
      #pragma unroll
      for (int j = 0; j < 4; ++j) {
        const int f = q * 64 + i * 4 + j;
        const float z = (vv[j] - shf[256 + f]) * shf[f];
        const float sg = 1.0f / (1.0f + __expf(-z));
        sgl[f * 128 + row] = (unsigned short)fminf(sg * 65536.0f, 65535.0f);
      }
    }
    ((s16x8*)Abuf[0])[tid * 2] = z8;
    ((s16x8*)Abuf[0])[tid * 2 + 1] = z8;
  }
  __syncthreads();

  const int wm = wid >> 2, wn = wid & 3;

  f32x4 acc[4][2];
  #pragma unroll
  for (int i = 0; i < 4; ++i)
    #pragma unroll
    for (int j = 0; j < 2; ++j)
      acc[i][j] = (f32x4){0.f, 0.f, 0.f, 0.f};

  for (int c = 0; c < NCHUNK; ++c) {
    const int buf = c & 1;
    short* Ab = Abuf[buf];
    short* Bb = Bbuf[buf];

    // ---------- P1: prefetch next tiles (DMA), scatter basis into pre-zeroed A ----------
    if (c + 1 < NCHUNK) {
      const char* gB = (const char*)Bws + ((size_t)(c + 1) * 4 + nt) * 16384 + tid * 16;
      gll16(gB,        (char*)Bbuf[buf ^ 1] + ldsoff);
      gll16(gB + 8192, (char*)Bbuf[buf ^ 1] + 8192 + ldsoff);
      if (c >= 127) {
        const char* gA = (const char*)Aws + ((size_t)mt * 4 + (c + 1 - 128)) * 16384 + tid * 16;
        gll16(gA,        (char*)Abuf[buf ^ 1] + ldsoff);
        gll16(gA + 8192, (char*)Abuf[buf ^ 1] + 8192 + ldsoff);
      }
    }
    if (c < 128 && tid < 256) {
      const int bp = tid & 127, fi = tid >> 7;
      const int f = 2 * c + fi;
      const float sg = ((float)sgl[f * 128 + bp] + 0.5f) * (1.0f / 65536.0f);
      int s0 = (int)floorf(sg * 29.0f);
      s0 = s0 < 0 ? 0 : (s0 > 28 ? 28 : s0);
      const int sp = s0 + 3;
      float Nv[4], lef[4], rig[4];
      Nv[0] = 1.0f;
      #pragma unroll
      for (int r = 1; r <= 3; ++r) {
        lef[r] = sg - knotv(sp + 1 - r);
        rig[r] = knotv(sp + r) - sg;
        float saved = 0.0f;
        #pragma unroll
        for (int j = 0; j < r; ++j) {
          float temp = fdiv_fast(Nv[j], rig[j + 1] + lef[r - j]);
          Nv[j] = saved + rig[j + 1] * temp;
          saved = lef[r - j] * temp;
        }
        Nv[r] = saved;
      }
      const int rg = bp >> 4, l15b = bp & 15;
      #pragma unroll
      for (int t = 0; t < 4; ++t) {
        const int g = s0 + t;
        Ab[((rg * 2 + fi) * 64 + (g >> 3) * 16 + l15b) * 8 + (g & 7)] = f2bf(Nv[t]);
      }
    }
    __syncthreads();   // b1: A scatter + B[c] DMA visible

    // ---------- P2: MFMA on (A[buf], B[buf]); zero A[buf^1] for the next scatter ----------
    {
      s16x8 bfv[2][2];
      #pragma unroll
      for (int nf = 0; nf < 2; ++nf)
        #pragma unroll
        for (int kk = 0; kk < 2; ++kk)
          bfv[nf][kk] = *(const s16x8*)&Bb[(((wn * 2 + nf) * 2 + kk) * 64 + lane) * 8];
      #pragma unroll
      for (int kk = 0; kk < 2; ++kk)
        #pragma unroll
        for (int mf = 0; mf < 4; ++mf) {
          s16x8 af = *(const s16x8*)&Ab[(((wm * 4 + mf) * 2 + kk) * 64 + lane) * 8];
          #pragma unroll
          for (int nf = 0; nf < 2; ++nf)
            acc[mf][nf] = __builtin_amdgcn_mfma_f32_16x16x32_bf16(af, bfv[nf][kk], acc[mf][nf], 0, 0, 0);
        }
    }
    if (c < 127) {
      short* An = Abuf[buf ^ 1];
      ((s16x8*)An)[tid * 2] = z8;
      ((s16x8*)An)[tid * 2 + 1] = z8;
    }
    __syncthreads();   // b2: MFMA reads done before next DMA/zero targets flip
  }

  // ---------- epilogue ----------
  const int l15 = lane & 15;
  const int lq = lane >> 4;
  #pragma unroll
  for (int nf = 0; nf < 2; ++nf) {
    const int col = n0 + wn * 32 + nf * 16 + l15;
    const float badd = bias[col] + skip_b[col];
    #pragma unroll
    for (int mf = 0; mf < 4; ++mf) {
      const int r0 = m0 + wm * 64 + mf * 16 + lq * 4;
      #pragma unroll
      for (int r = 0; r < 4; ++r)
        out[(size_t)(r0 + r) * W + col] = acc[mf][nf][r] + badd;
    }
  }
}

// ---------------- fallback GEMM (no ws) — round-2 kernel ----------------
__device__ __forceinline__ void issue_b(int c, int uu, int n0,
                                        const float* __restrict__ coeffs,
                                        const float* __restrict__ skip_w,
                                        float (&r)[4][8]) {
  const float* base = (c < 128) ? (coeffs + (size_t)c * 64 * W)
                                : (skip_w + (size_t)(c - 128) * 64 * W);
  const int kk = (uu >> 6) & 1;
  const int lq = (uu >> 4) & 3;
  const int l15 = uu & 15;
  const int u7 = uu >> 7;
  #pragma unroll
  for (int s = 0; s < 4; ++s) {
    const int w = (2 * s + u7) * 16 + l15;
    const float* p = base + (size_t)(kk * 32 + lq * 8) * W + n0 + w;
    #pragma unroll
    for (int j = 0; j < 8; ++j) r[s][j] = p[(size_t)j * W];
  }
}

__global__ __launch_bounds__(512, 1) void kan_gemm_v2(
    const float* __restrict__ inp, const float* __restrict__ shift,
    const float* __restrict__ lscale, const float* __restrict__ coeffs,
    const float* __restrict__ bias, const float* __restrict__ skip_w,
    const float* __restrict__ skip_b, float* __restrict__ out)
{
  __shared__ short Abuf[2][8192];
  __shared__ short Bbuf[2][8192];
  __shared__ unsigned short sgl[F * 128];

  const int tid = threadIdx.x;
  const int lane = tid & 63;
  const int wid = tid >> 6;
  const int nb = (blockIdx.x & 7) * 32 + (blockIdx.x >> 3);
  const int mt = nb >> 2;
  const int nt = nb & 3;
  const int m0 = mt * 128;
  const int n0 = nt * 128;

  float bpref[4][8];
  if (tid >= 256) issue_b(0, tid - 256, n0, coeffs, skip_w, bpref);

  float* shf = (float*)&Abuf[0][0];
  if (tid < 256) {
    float ls = lscale[tid];
    shf[tid] = fmaxf(ls, 0.0f) + __logf(1.0f + __expf(-fabsf(ls))) + 0.001f;
    shf[256 + tid] = shift[tid];
  }
  __syncthreads();

  {
    const int row = tid & 127;
    const int q = tid >> 7;
    const float* ip = inp + (size_t)(m0 + row) * F + q * 64;
    #pragma unroll
    for (int i = 0; i < 16; ++i) {
      float4 v = *(const float4*)(ip + i * 4);
      float vv[4] = {v.x, v.y, v.z, v.w};
      #pragma unroll
      for (int j = 0; j < 4; ++j) {
        const int f = q * 64 + i * 4 + j;
        const float z = (vv[j] - shf[256 + f]) * shf[f];
        const float sg = 1.0f / (1.0f + __expf(-z));
        sgl[f * 128 + row] = (unsigned short)fminf(sg * 65536.0f, 65535.0f);
      }
    }
  }
  __syncthreads();

  const int wm = wid >> 2;
  const int wn = wid & 3;

  f32x4 acc[4][2];
  #pragma unroll
  for (int i = 0; i < 4; ++i)
    #pragma unroll
    for (int j = 0; j < 2; ++j)
      acc[i][j] = (f32x4){0.f, 0.f, 0.f, 0.f};

  for (int c = 0; c < NCHUNK; ++c) {
    short* Ab = Abuf[c & 1];
    short* Bb = Bbuf[c & 1];

    if (c < 128) {
      s16x8 z = {0, 0, 0, 0, 0, 0, 0, 0};
      ((s16x8*)Ab)[tid * 2] = z;
      ((s16x8*)Ab)[tid * 2 + 1] = z;
    } else if (tid < 256) {
      const int bp = tid & 127, fi = tid >> 7;
      const int sb = (c - 128) * 64 + fi * 32;
      const float* ip = inp + (size_t)(m0 + bp) * F + sb;
      const int rg = bp >> 4, l15b = bp & 15;
      #pragma unroll
      for (int lq2 = 0; lq2 < 4; ++lq2) {
        s16x8 h;
        #pragma unroll
        for (int j = 0; j < 8; ++j) h[j] = f2bf(ip[lq2 * 8 + j]);
        *(s16x8*)&Ab[((rg * 2 + fi) * 64 + lq2 * 16 + l15b) * 8] = h;
      }
    }
    if (tid >= 256) {
      const int uu = tid - 256;
      #pragma unroll
      for (int s = 0; s < 4; ++s) {
        s16x8 h;
        #pragma unroll
        for (int j = 0; j < 8; ++j) h[j] = f2bf(bpref[s][j]);
        *(s16x8*)&Bb[(s * 256 + uu) * 8] = h;
      }
      if (c + 1 < NCHUNK) issue_b(c + 1, uu, n0, coeffs, skip_w, bpref);
    }
    __syncthreads();

    if (c < 128 && tid < 256) {
      const int bp = tid & 127, fi = tid >> 7;
      const int f = 2 * c + fi;
      const float sg = ((float)sgl[f * 128 + bp] + 0.5f) * (1.0f / 65536.0f);
      int s0 = (int)floorf(sg * 29.0f);
      s0 = s0 < 0 ? 0 : (s0 > 28 ? 28 : s0);
      const int sp = s0 + 3;
      float Nv[4], lef[4], rig[4];
      Nv[0] = 1.0f;
      #pragma unroll
      for (int r = 1; r <= 3; ++r) {
        lef[r] = sg - knotv(sp + 1 - r);
        rig[r] = knotv(sp + r) - sg;
        float saved = 0.0f;
        #pragma unroll
        for (int j = 0; j < r; ++j) {
          float temp = fdiv_fast(Nv[j], rig[j + 1] + lef[r - j]);
          Nv[j] = saved + rig[j + 1] * temp;
          saved = lef[r - j] * temp;
        }
        Nv[r] = saved;
      }
      const int rg = bp >> 4, l15b = bp & 15;
      #pragma unroll
      for (int t = 0; t < 4; ++t) {
        const int g = s0 + t;
        Ab[((rg * 2 + fi) * 64 + (g >> 3) * 16 + l15b) * 8 + (g & 7)] = f2bf(Nv[t]);
      }
    }
    s16x8 bfv[2][2];
    #pragma unroll
    for (int nf = 0; nf < 2; ++nf)
      #pragma unroll
      for (int kk = 0; kk < 2; ++kk)
        bfv[nf][kk] = *(const s16x8*)&Bb[(((wn * 2 + nf) * 2 + kk) * 64 + lane) * 8];
    __syncthreads();

    #pragma unroll
    for (int kk = 0; kk < 2; ++kk) {
      #pragma unroll
      for (int mf = 0; mf < 4; ++mf) {
        s16x8 af = *(const s16x8*)&Ab[(((wm * 4 + mf) * 2 + kk) * 64 + lane) * 8];
        #pragma unroll
        for (int nf = 0; nf < 2; ++nf)
          acc[mf][nf] = __builtin_amdgcn_mfma_f32_16x16x32_bf16(af, bfv[nf][kk], acc[mf][nf], 0, 0, 0);
      }
    }
  }

  const int l15 = lane & 15;
  const int lq = lane >> 4;
  #pragma unroll
  for (int nf = 0; nf < 2; ++nf) {
    const int col = n0 + wn * 32 + nf * 16 + l15;
    const float badd = bias[col] + skip_b[col];
    #pragma unroll
    for (int mf = 0; mf < 4; ++mf) {
      const int r0 = m0 + wm * 64 + mf * 16 + lq * 4;
      #pragma unroll
      for (int r = 0; r < 4; ++r)
        out[(size_t)(r0 + r) * W + col] = acc[mf][nf][r] + badd;
    }
  }
}

__global__ __launch_bounds__(256, 1) void ln_gelu(
    float* __restrict__ out, const float* __restrict__ gamma,
    const float* __restrict__ beta)
{
  const int lane = threadIdx.x & 63;
  const int wid = threadIdx.x >> 6;
  const int row = blockIdx.x * 4 + wid;
  float* p = out + (size_t)row * W + lane * 8;
  float4 a = *(const float4*)p;
  float4 b = *(const float4*)(p + 4);
  float v[8] = {a.x, a.y, a.z, a.w, b.x, b.y, b.z, b.w};
  float s = 0.f, q = 0.f;
  #pragma unroll
  for (int j = 0; j < 8; ++j) { s += v[j]; q += v[j] * v[j]; }
  #pragma unroll
  for (int m = 1; m < 64; m <<= 1) {
    s += __shfl_xor(s, m);
    q += __shfl_xor(q, m);
  }
  const float mu = s * (1.0f / 512.0f);
  const float var = q * (1.0f / 512.0f) - mu * mu;
  const float inv = rsqrtf(var + 1e-5f);
  const float4 g0 = *(const float4*)(gamma + lane * 8);
  const float4 g1 = *(const float4*)(gamma + lane * 8 + 4);
  const float4 b0 = *(const float4*)(beta + lane * 8);
  const float4 b1 = *(const float4*)(beta + lane * 8 + 4);
  float gm[8] = {g0.x, g0.y, g0.z, g0.w, g1.x, g1.y, g1.z, g1.w};
  float bt[8] = {b0.x, b0.y, b0.z, b0.w, b1.x, b1.y, b1.z, b1.w};
  float o[8];
  #pragma unroll
  for (int j = 0; j < 8; ++j) {
    float x = (v[j] - mu) * inv * gm[j] + bt[j];
    o[j] = 0.5f * x * (1.0f + erff(x * 0.70710678f));
  }
  float4 w0 = {o[0], o[1], o[2], o[3]};
  float4 w1 = {o[4], o[5], o[6], o[7]};
  *(float4*)p = w0;
  *(float4*)(p + 4) = w1;
}

extern "C" void kernel_launch(void* const* d_in, const int* in_sizes, int n_in,
                              void* d_out, int out_size, void* d_ws, size_t ws_size,
                              hipStream_t stream) {
  (void)in_sizes; (void)n_in; (void)out_size;
  const float* inp    = (const float*)d_in[0];
  const float* shift  = (const float*)d_in[1];
  const float* lscale = (const float*)d_in[2];
  const float* coeffs = (const float*)d_in[3];
  const float* bias   = (const float*)d_in[4];
  const float* skip_w = (const float*)d_in[5];
  const float* skip_b = (const float*)d_in[6];
  const float* gamma  = (const float*)d_in[7];
  const float* beta   = (const float*)d_in[8];
  float* out = (float*)d_out;

  const size_t needB = (size_t)NCHUNK * 4 * 16384;   // 8,650,752
  const size_t needA = (size_t)64 * 4 * 16384;       // 4,194,304

  if (ws_size >= needB + needA) {
    short* Bws = (short*)d_ws;
    short* Aws = (short*)((char*)d_ws + needB);
    bws_build<<<dim3(2112), dim3(256), 0, stream>>>(coeffs, skip_w, Bws);
    aws_build<<<dim3(1024), dim3(256), 0, stream>>>(inp, Aws);
    kan_gemm_v3<<<dim3(256), dim3(512), 0, stream>>>(
        inp, shift, lscale, Bws, Aws, bias, skip_b, out);
  } else {
    kan_gemm_v2<<<dim3(256), dim3(512), 0, stream>>>(
        inp, shift, lscale, coeffs, bias, skip_w, skip_b, out);
  }
  ln_gelu<<<dim3(BATCH / 4), dim3(256), 0, stream>>>(out, gamma, beta);
}